// Round 11
// baseline (47725.754 us; speedup 1.0000x reference)
//
#include <hip/hip_runtime.h>
#include <hip/hip_cooperative_groups.h>
#include <hip/hip_bf16.h>
#include <math.h>

namespace cg = cooperative_groups;

// Problem config (fixed)
#define BB 32      // batch
#define TT 128     // time steps
#define UU 1024    // units
#define MM 8       // memory slots
#define LL 9       // M+1
#define RR 17      // 2M+1
#define MROWS 288  // BB*LL
#define NBLK 224   // persistent blocks: 160 W1 + 32 Wm1 + 32 Wm2

typedef __bf16 bf16x8 __attribute__((ext_vector_type(8)));
typedef float f32x4 __attribute__((ext_vector_type(4)));
typedef float f32x8 __attribute__((ext_vector_type(8)));

// exact 3-way bf16 split: v = x1 + x2 + x3 + O(2^-27 v)
__device__ __forceinline__ void split3(float v, __bf16* x1, __bf16* x2, __bf16* x3)
{
    __bf16 h1 = (__bf16)v;  float r = v - (float)h1;
    __bf16 h2 = (__bf16)r;  r -= (float)h2;
    *x1 = h1; *x2 = h2; *x3 = (__bf16)r;
}

__device__ __forceinline__ void split8(const f32x8 v, bf16x8& a, bf16x8& b, bf16x8& c)
{
#pragma unroll
    for (int j = 0; j < 8; ++j) {
        float f = v[j];
        __bf16 h1 = (__bf16)f; float r = f - (float)h1;
        __bf16 h2 = (__bf16)r; r -= (float)h2;
        a[j] = h1; b[j] = h2; c[j] = (__bf16)r;
    }
}

__device__ __forceinline__ float gelu_f(float x)
{
    float t = tanhf(0.7978845608028654f * (x + 0.044715f * x * x * x));
    return 0.5f * x * (1.f + t);
}

struct PArgs {
    const float* xp_all;   // [4096,1024]
    const float* gx_all;   // [4096,2048]
    const float* rproj;    // [17,1024]
    const float* b1;       // [5120]
    const float* bm;       // [2048]
    const float* gam;      // [2048]
    const float* bet;      // [2048]
    const __bf16 *W1a, *W1b, *W1c;   // [5120,1024]
    const __bf16 *Wma, *Wmb, *Wmc;   // [2048,1024]
    float* mp;     // [288,1024]
    float* qkvg;   // [288,5120]  (bias baked in)
    float* a1;     // [288,1024]
    float* hbuf;   // [288,1024]
    float* m2;     // [288,1024]
    float* out;    // [32,128,1024]
};

// ---- LDS-weight split-6 GEMM over all 288 rows x block's 32 cols, full K ----
// smem: plane b1 (and b2 if NPL==2), 32 cols x 1024 k bf16, XOR-swizzled.
// b3 (and b2 if NPL==1) streamed from global.
template<int NPL, int ACT>
__device__ __forceinline__ void lds_gemm(const char* smem,
    const float* __restrict__ A, const __bf16* __restrict__ B2g,
    const __bf16* __restrict__ B3g, int gcol0,
    const float* __restrict__ biasp, float* __restrict__ C,
    int ldc, int ccol0, int wave, int lane)
{
    int lr = lane & 15, kg = lane >> 4;
    for (int s = wave; s < 18; s += 8) {
        int row0 = s * 16;
        const float* Ap = A + (size_t)(row0 + lr) * 1024 + kg * 8;
        f32x4 accA = {0.f, 0.f, 0.f, 0.f}, accB = {0.f, 0.f, 0.f, 0.f};
        for (int kk = 0; kk < 32; ++kk) {
            f32x8 af = *(const f32x8*)(Ap + kk * 32);
            bf16x8 a1v, a2v, a3v;
            split8(af, a1v, a2v, a3v);
#pragma unroll
            for (int ct = 0; ct < 2; ++ct) {
                int col = ct * 16 + lr;
                int byte = col * 2048 + ((kk * 64 + kg * 16) ^ ((col & 7) << 4));
                bf16x8 b1 = *(const bf16x8*)(smem + byte);
                bf16x8 b2 = (NPL == 2)
                    ? *(const bf16x8*)(smem + 65536 + byte)
                    : *(const bf16x8*)(B2g + (size_t)(gcol0 + col) * 1024 + kk * 32 + kg * 8);
                bf16x8 b3 = *(const bf16x8*)(B3g + (size_t)(gcol0 + col) * 1024 + kk * 32 + kg * 8);
                f32x4& acc = ct ? accB : accA;
                acc = __builtin_amdgcn_mfma_f32_16x16x32_bf16(a1v, b1, acc, 0, 0, 0);
                acc = __builtin_amdgcn_mfma_f32_16x16x32_bf16(a1v, b2, acc, 0, 0, 0);
                acc = __builtin_amdgcn_mfma_f32_16x16x32_bf16(a2v, b1, acc, 0, 0, 0);
                acc = __builtin_amdgcn_mfma_f32_16x16x32_bf16(a1v, b3, acc, 0, 0, 0);
                acc = __builtin_amdgcn_mfma_f32_16x16x32_bf16(a2v, b2, acc, 0, 0, 0);
                acc = __builtin_amdgcn_mfma_f32_16x16x32_bf16(a3v, b1, acc, 0, 0, 0);
            }
        }
        int r0 = row0 + kg * 4;
#pragma unroll
        for (int ct = 0; ct < 2; ++ct) {
            const f32x4& acc = ct ? accB : accA;
            int col = ct * 16 + lr;
            float bv = biasp[col];
#pragma unroll
            for (int r = 0; r < 4; ++r) {
                float v = acc[r] + bv;
                if (ACT) v = gelu_f(v);
                C[(size_t)(r0 + r) * ldc + ccol0 + col] = v;
            }
        }
    }
}

// ---- attention + LN1 for batch b (512 thr; attn vals held in registers) ----
__device__ __forceinline__ void attn_ln_body(const PArgs& a, int b, int tid,
                                             float* red)
{
    int wave = tid >> 6, lane = tid & 63;
    float attnv[2][LL];
    for (int hh = 0; hh < 2; ++hh) {
        int h = wave + hh * 8;
        const float* base = a.qkvg + (size_t)b * LL * 5120 + h * 64 + lane;
        float q[LL], k[LL], v[LL], r[RR];
#pragma unroll
        for (int l = 0; l < LL; ++l) {
            q[l] = base[l * 5120];
            k[l] = base[l * 5120 + 1024];
            v[l] = base[l * 5120 + 2048];
        }
#pragma unroll
        for (int rp = 0; rp < RR; ++rp) r[rp] = a.rproj[rp * UU + h * 64 + lane];
#pragma unroll
        for (int qr = 0; qr < LL; ++qr) {
            float sc[LL];
#pragma unroll
            for (int kr = 0; kr < LL; ++kr) {
                float prod = q[qr] * (k[kr] + r[qr - kr + MM]);
#pragma unroll
                for (int o = 32; o > 0; o >>= 1) prod += __shfl_xor(prod, o);
                sc[kr] = prod * 0.125f;
            }
            float m = sc[0];
#pragma unroll
            for (int kr = 1; kr < LL; ++kr) m = fmaxf(m, sc[kr]);
            float s = 0.f;
#pragma unroll
            for (int kr = 0; kr < LL; ++kr) { sc[kr] = expf(sc[kr] - m); s += sc[kr]; }
            float inv = 1.0f / s;
            float acc = 0.f;
#pragma unroll
            for (int kr = 0; kr < LL; ++kr) acc += sc[kr] * v[kr];
            attnv[hh][qr] = acc * inv;
        }
    }
    // LN1: same reduction tree as R3/R6 (pairs tid, tid+512)
#pragma unroll
    for (int qr = 0; qr < LL; ++qr) {
        size_t row = (size_t)(b * LL + qr) * UU;
        float x0 = a.mp[row + tid] + attnv[0][qr];
        float x1 = a.mp[row + tid + 512] + attnv[1][qr];
        float s = x0 + x1, ss = x0 * x0 + x1 * x1;
#pragma unroll
        for (int o = 32; o > 0; o >>= 1) { s += __shfl_xor(s, o); ss += __shfl_xor(ss, o); }
        if (lane == 0) { red[qr * 16 + wave * 2] = s; red[qr * 16 + wave * 2 + 1] = ss; }
    }
    __syncthreads();
#pragma unroll
    for (int qr = 0; qr < LL; ++qr) {
        float S = 0.f, SS = 0.f;
#pragma unroll
        for (int w = 0; w < 8; ++w) { S += red[qr * 16 + w * 2]; SS += red[qr * 16 + w * 2 + 1]; }
        float mean = S * (1.0f / UU);
        float rstd = rsqrtf(SS * (1.0f / UU) - mean * mean + 1e-6f);
        size_t row = (size_t)(b * LL + qr) * UU;
        float x0 = a.mp[row + tid] + attnv[0][qr];
        float x1 = a.mp[row + tid + 512] + attnv[1][qr];
        a.a1[row + tid]       = (x0 - mean) * rstd * a.gam[tid] + a.bet[tid];
        a.a1[row + tid + 512] = (x1 - mean) * rstd * a.gam[tid + 512] + a.bet[tid + 512];
    }
    __syncthreads();
}

// ---- finalize: LN2 + gates + memory update + output for one row (512 thr) ----
__device__ __forceinline__ void finalize_body(const PArgs& a, int row, int t,
                                              int tid, float* red)
{
    int b = row / LL, l = row % LL;
    int wave = tid >> 6, lane = tid & 63;
    float x[2];
    float s = 0.f, ss = 0.f;
#pragma unroll
    for (int j = 0; j < 2; ++j) {
        int u = tid + j * 512;
        x[j] = a.a1[(size_t)row * UU + u] + a.m2[(size_t)row * UU + u];
        s += x[j]; ss += x[j] * x[j];
    }
#pragma unroll
    for (int o = 32; o > 0; o >>= 1) { s += __shfl_xor(s, o); ss += __shfl_xor(ss, o); }
    if (lane == 0) { red[wave * 2] = s; red[wave * 2 + 1] = ss; }
    __syncthreads();
    float S = 0.f, SS = 0.f;
#pragma unroll
    for (int w = 0; w < 8; ++w) { S += red[w * 2]; SS += red[w * 2 + 1]; }
    __syncthreads();
    float mean = S * (1.0f / UU);
    float rstd = rsqrtf(SS * (1.0f / UU) - mean * mean + 1e-6f);

    size_t gxoff = ((size_t)b * TT + t) * 2048;
    size_t grow = (size_t)row * 5120 + 3072;
#pragma unroll
    for (int j = 0; j < 2; ++j) {
        int u = tid + j * 512;
        float cand = (x[j] - mean) * rstd * a.gam[1024 + u] + a.bet[1024 + u];
        float tc = tanhf(cand);
        float gi = a.gx_all[gxoff + u]        + a.qkvg[grow + u];
        float gf = a.gx_all[gxoff + 1024 + u] + a.qkvg[grow + 1024 + u];
        float ig = fminf(fmaxf(0.2f * gi + 0.5f, 0.f), 1.f);
        float fg = fminf(fmaxf(0.2f * (gf + 1.0f) + 0.5f, 0.f), 1.f);
        size_t off = (size_t)row * UU + u;
        float nmp = fg * a.mp[off] + ig * tc;
        if (l < MM) {
            a.mp[off] = nmp;
        } else {
            a.out[((size_t)b * TT + t) * UU + u] = nmp;
            if (t + 1 < TT)
                a.mp[off] = a.xp_all[((size_t)b * TT + t + 1) * UU + u];
        }
    }
    __syncthreads();
}

// ---------------- persistent weight-stationary scan kernel ----------------
template<int NPL>
__global__ __launch_bounds__(512) void scan_kernel(PArgs a)
{
    cg::grid_group grid = cg::this_grid();
    extern __shared__ __align__(16) char smem[];
    __shared__ float red[160];
    int bid = blockIdx.x, tid = threadIdx.x;
    int wave = tid >> 6, lane = tid & 63;

    // role: weight columns owned by this block
    const __bf16 *ga, *gb;
    int gcol0;
    if (bid < 160)      { ga = a.W1a; gb = a.W1b; gcol0 = bid * 32; }
    else if (bid < 192) { ga = a.Wma; gb = a.Wmb; gcol0 = (bid - 160) * 32; }
    else                { ga = a.Wma; gb = a.Wmb; gcol0 = 1024 + (bid - 192) * 32; }

    // one-time LDS weight load (XOR-swizzled)
    for (int idx = tid; idx < 32 * 128; idx += 512) {
        int col = idx >> 7, kc = idx & 127;
        int sw = (kc * 16) ^ ((col & 7) << 4);
        *(bf16x8*)(smem + (size_t)col * 2048 + sw) =
            *(const bf16x8*)(ga + (size_t)(gcol0 + col) * 1024 + kc * 8);
        if (NPL == 2)
            *(bf16x8*)(smem + 65536 + (size_t)col * 2048 + sw) =
                *(const bf16x8*)(gb + (size_t)(gcol0 + col) * 1024 + kc * 8);
    }
    __syncthreads();

    for (int t = 0; t < TT; ++t) {
        // phase A: qkvg = mp @ [Wa|Wr] + b1  (160 blocks)
        if (bid < 160)
            lds_gemm<NPL, 0>(smem, a.mp, a.W1b, a.W1c, bid * 32,
                             a.b1 + bid * 32, a.qkvg, 5120, bid * 32, wave, lane);
        grid.sync();
        // phase B: attention + LN1 (32 blocks)
        if (bid < BB) attn_ln_body(a, bid, tid, red);
        grid.sync();
        // phase C: hbuf = gelu(a1 @ Wm1 + bm1) (32 blocks)
        if (bid >= 160 && bid < 192)
            lds_gemm<NPL, 1>(smem, a.a1, a.Wmb, a.Wmc, (bid - 160) * 32,
                             a.bm + (bid - 160) * 32, a.hbuf, UU,
                             (bid - 160) * 32, wave, lane);
        grid.sync();
        // phase D: m2 = hbuf @ Wm2 + bm2 (32 blocks)
        if (bid >= 192)
            lds_gemm<NPL, 0>(smem, a.hbuf, a.Wmb, a.Wmc, 1024 + (bid - 192) * 32,
                             a.bm + 1024 + (bid - 192) * 32, a.m2, UU,
                             (bid - 192) * 32, wave, lane);
        grid.sync();
        // phase E: finalize (224 blocks cover 288 rows)
        for (int row = bid; row < MROWS; row += NBLK)
            finalize_body(a, row, t, tid, red);
        grid.sync();
    }
}

// ---------------- fallback per-phase kernels ----------------
__global__ __launch_bounds__(512) void attn_k(PArgs a)
{
    __shared__ float red[160];
    attn_ln_body(a, blockIdx.x, threadIdx.x, red);
}
__global__ __launch_bounds__(512) void finalize_k(PArgs a, int t)
{
    __shared__ float red[160];
    finalize_body(a, blockIdx.x, t, threadIdx.x, red);
}

// ---- direct split6 GEMM (prep + fallback): one 16x64 wave tile ----
__device__ __forceinline__ void tile6(
    const float* __restrict__ A,
    const __bf16* __restrict__ B1, const __bf16* __restrict__ B2,
    const __bf16* __restrict__ B3,
    const float* __restrict__ bias, float* __restrict__ C,
    int ldc, int act, int row0, int col0, int lane)
{
    int lr = lane & 15, kofs = (lane >> 4) * 8;
    const float* Ap = A + (size_t)(row0 + lr) * 1024 + kofs;
    size_t boff = (size_t)(col0 + lr) * 1024 + kofs;
    f32x4 acc[4];
#pragma unroll
    for (int c = 0; c < 4; ++c) acc[c] = (f32x4){0.f, 0.f, 0.f, 0.f};

    for (int k = 0; k < 1024; k += 32) {
        f32x8 af = *(const f32x8*)(Ap + k);
        bf16x8 a1, a2, a3;
        split8(af, a1, a2, a3);
#pragma unroll
        for (int c = 0; c < 4; ++c) {
            size_t o = boff + (size_t)c * 16 * 1024 + k;
            bf16x8 b1 = *(const bf16x8*)(B1 + o);
            bf16x8 b2 = *(const bf16x8*)(B2 + o);
            bf16x8 b3 = *(const bf16x8*)(B3 + o);
            acc[c] = __builtin_amdgcn_mfma_f32_16x16x32_bf16(a1, b1, acc[c], 0, 0, 0);
            acc[c] = __builtin_amdgcn_mfma_f32_16x16x32_bf16(a1, b2, acc[c], 0, 0, 0);
            acc[c] = __builtin_amdgcn_mfma_f32_16x16x32_bf16(a2, b1, acc[c], 0, 0, 0);
            acc[c] = __builtin_amdgcn_mfma_f32_16x16x32_bf16(a1, b3, acc[c], 0, 0, 0);
            acc[c] = __builtin_amdgcn_mfma_f32_16x16x32_bf16(a2, b2, acc[c], 0, 0, 0);
            acc[c] = __builtin_amdgcn_mfma_f32_16x16x32_bf16(a3, b1, acc[c], 0, 0, 0);
        }
    }

    int r0 = row0 + (lane >> 4) * 4;
#pragma unroll
    for (int c = 0; c < 4; ++c) {
        int col = col0 + c * 16 + lr;
        float bv = bias ? bias[col] : 0.f;
#pragma unroll
        for (int r = 0; r < 4; ++r) {
            float v = acc[c][r] + bv;
            if (act == 1) v = gelu_f(v);
            C[(size_t)(r0 + r) * ldc + col] = v;
        }
    }
}

__global__ __launch_bounds__(256) void gemm6(
    const float* __restrict__ A,
    const __bf16* __restrict__ B1, const __bf16* __restrict__ B2,
    const __bf16* __restrict__ B3,
    const float* __restrict__ bias, float* __restrict__ C, int ldc, int act)
{
    int wave = threadIdx.x >> 6, lane = threadIdx.x & 63;
    int row0 = blockIdx.y * 32 + (wave >> 1) * 16;
    int col0 = blockIdx.x * 128 + (wave & 1) * 64;
    tile6(A, B1, B2, B3, bias, C, ldc, act, row0, col0, lane);
}

// ---------- weight transpose + 3-way split: out[N,1024] planes = in[1024,N]^T
__global__ __launch_bounds__(256) void transpose_split(
    const float* __restrict__ in,
    __bf16* __restrict__ o1, __bf16* __restrict__ o2, __bf16* __restrict__ o3,
    int N)
{
    __shared__ float t[32][33];
    int tx = threadIdx.x & 31, ty = threadIdx.x >> 5;
    int k0 = blockIdx.y * 32, n0 = blockIdx.x * 32;
#pragma unroll
    for (int i = 0; i < 4; ++i)
        t[ty + i * 8][tx] = in[(size_t)(k0 + ty + i * 8) * N + n0 + tx];
    __syncthreads();
#pragma unroll
    for (int i = 0; i < 4; ++i) {
        float v = t[tx][ty + i * 8];
        size_t off = (size_t)(n0 + ty + i * 8) * 1024 + k0 + tx;
        split3(v, o1 + off, o2 + off, o3 + off);
    }
}

// ---------------- tiny fp32 GEMM (one-time rproj) ----------------
#define BKK 16
__global__ __launch_bounds__(256) void gemm_f32(
    const float* __restrict__ A, const float* __restrict__ B,
    float* __restrict__ C, int M, int N, int K)
{
    __shared__ float As[BKK][65];
    __shared__ float Bs[BKK][64];
    int tid = threadIdx.x;
    int row0 = blockIdx.y * 64, col0 = blockIdx.x * 64;
    int ty = tid >> 4, tx = tid & 15;
    float acc[4][4];
#pragma unroll
    for (int i = 0; i < 4; ++i)
#pragma unroll
        for (int j = 0; j < 4; ++j) acc[i][j] = 0.f;
    for (int k0 = 0; k0 < K; k0 += BKK) {
        {
            int r = tid >> 2, kv = (tid & 3) * 4;
            float4 v = make_float4(0.f, 0.f, 0.f, 0.f);
            int gr = row0 + r;
            if (gr < M) v = *(const float4*)(A + (size_t)gr * K + k0 + kv);
            As[kv + 0][r] = v.x; As[kv + 1][r] = v.y;
            As[kv + 2][r] = v.z; As[kv + 3][r] = v.w;
        }
        {
            int r = tid >> 4, cv = (tid & 15) * 4;
            float4 v = *(const float4*)(B + (size_t)(k0 + r) * N + col0 + cv);
            *(float4*)&Bs[r][cv] = v;
        }
        __syncthreads();
#pragma unroll
        for (int kk = 0; kk < BKK; ++kk) {
            float a[4], b[4];
#pragma unroll
            for (int j = 0; j < 4; ++j) a[j] = As[kk][ty * 4 + j];
#pragma unroll
            for (int j = 0; j < 4; ++j) b[j] = Bs[kk][tx * 4 + j];
#pragma unroll
            for (int i = 0; i < 4; ++i)
#pragma unroll
                for (int j = 0; j < 4; ++j) acc[i][j] += a[i] * b[j];
        }
        __syncthreads();
    }
#pragma unroll
    for (int i = 0; i < 4; ++i) {
        int gr = row0 + ty * 4 + i;
        if (gr >= M) continue;
#pragma unroll
        for (int j = 0; j < 4; ++j)
            C[(size_t)gr * N + col0 + tx * 4 + j] = acc[i][j];
    }
}

// ---------------- relative embedding table ----------------
__global__ void relemb_kernel(float* __restrict__ tab)
{
    int p = blockIdx.x;
    float pv = (float)(p - MM);
    for (int i = threadIdx.x; i < UU; i += blockDim.x) {
        float expo = (float)(i & ~1) * (1.0f / (float)UU);
        float scale = exp2f(-expo * 13.287712379549449f);  // 10000^-expo
        float ang = pv * scale;
        tab[p * UU + i] = (i & 1) ? cosf(ang) : sinf(ang);
    }
}

// ---------------- init mp ----------------
__global__ void init_mp(const float* __restrict__ xp_all, float* __restrict__ mp)
{
    int row = blockIdx.x;
    int b = row / LL, l = row % LL;
    for (int u = threadIdx.x; u < UU; u += blockDim.x)
        mp[(size_t)row * UU + u] = (l == MM) ? xp_all[((size_t)b * TT) * UU + u] : 0.f;
}

// ---------------- host launcher ----------------
extern "C" void kernel_launch(void* const* d_in, const int* in_sizes, int n_in,
                              void* d_out, int out_size, void* d_ws, size_t ws_size,
                              hipStream_t stream)
{
    const float* x    = (const float*)d_in[0];
    const float* Wi   = (const float*)d_in[1];
    const float* bi   = (const float*)d_in[2];
    const float* Wg   = (const float*)d_in[3];
    const float* Wr   = (const float*)d_in[4];
    const float* br   = (const float*)d_in[5];
    const float* Wa   = (const float*)d_in[6];
    const float* ba   = (const float*)d_in[7];
    const float* Wm   = (const float*)d_in[8];
    const float* bm   = (const float*)d_in[9];
    const float* gam  = (const float*)d_in[10];
    const float* bet  = (const float*)d_in[11];
    const float* Wrel = (const float*)d_in[12];
    float* out = (float*)d_out;

    // ---- workspace layout ----
    char* w = (char*)d_ws;
    float*  xp_all = (float*)w;  w += (size_t)BB*TT*UU*4;        // 16.8 MB
    float*  gx_all = (float*)w;  w += (size_t)BB*TT*2048*4;      // 33.6 MB
    size_t W1N = (size_t)5120 * 1024, WMN = (size_t)2048 * 1024;
    __bf16* W1a = (__bf16*)w;    w += W1N*2;
    __bf16* W1b = (__bf16*)w;    w += W1N*2;
    __bf16* W1c = (__bf16*)w;    w += W1N*2;
    __bf16* Wma = (__bf16*)w;    w += WMN*2;
    __bf16* Wmb = (__bf16*)w;    w += WMN*2;
    __bf16* Wmc = (__bf16*)w;    w += WMN*2;
    float*  b1    = (float*)w;   w += 5120*4;
    float*  tab   = (float*)w;   w += RR*UU*4;
    float*  rproj = (float*)w;   w += RR*UU*4;
    float*  mp    = (float*)w;   w += (size_t)MROWS*UU*4;
    float*  qkvg  = (float*)w;   w += (size_t)MROWS*5120*4;
    float*  a1    = (float*)w;   w += (size_t)MROWS*UU*4;
    float*  hbuf  = (float*)w;   w += (size_t)MROWS*UU*4;
    float*  m2    = (float*)w;   w += (size_t)MROWS*UU*4;
    // prep-only planes for Wi/Wg (dedicated region)
    __bf16* Wia = (__bf16*)w;    w += (size_t)1024*1024*2;
    __bf16* Wib = (__bf16*)w;    w += (size_t)1024*1024*2;
    __bf16* Wic = (__bf16*)w;    w += (size_t)1024*1024*2;
    __bf16* Wga = (__bf16*)w;    w += (size_t)2048*1024*2;
    __bf16* Wgb = (__bf16*)w;    w += (size_t)2048*1024*2;
    __bf16* Wgc = (__bf16*)w;    w += (size_t)2048*1024*2;

    // ---- one-time prep ----
    relemb_kernel<<<RR, 256, 0, stream>>>(tab);
    gemm_f32<<<dim3(UU / 64, 1), 256, 0, stream>>>(tab, Wrel, rproj, RR, UU, UU);
    transpose_split<<<dim3(3072 / 32, 32), 256, 0, stream>>>(Wa, W1a, W1b, W1c, 3072);
    transpose_split<<<dim3(2048 / 32, 32), 256, 0, stream>>>(
        Wr, W1a + (size_t)3072 * 1024, W1b + (size_t)3072 * 1024,
        W1c + (size_t)3072 * 1024, 2048);
    transpose_split<<<dim3(2048 / 32, 32), 256, 0, stream>>>(Wm, Wma, Wmb, Wmc, 2048);
    transpose_split<<<dim3(1024 / 32, 32), 256, 0, stream>>>(Wi, Wia, Wib, Wic, 1024);
    transpose_split<<<dim3(2048 / 32, 32), 256, 0, stream>>>(Wg, Wga, Wgb, Wgc, 2048);
    hipMemcpyAsync(b1, ba, 3072 * sizeof(float), hipMemcpyDeviceToDevice, stream);
    hipMemcpyAsync(b1 + 3072, br, 2048 * sizeof(float), hipMemcpyDeviceToDevice, stream);
    gemm6<<<dim3(UU / 128, (BB * TT) / 32), 256, 0, stream>>>(
        x, Wia, Wib, Wic, bi, xp_all, UU, 0);
    gemm6<<<dim3(2048 / 128, (BB * TT) / 32), 256, 0, stream>>>(
        x, Wga, Wgb, Wgc, nullptr, gx_all, 2048, 0);
    init_mp<<<MROWS, 256, 0, stream>>>(xp_all, mp);

    // ---- persistent weight-stationary scan ----
    PArgs sa;
    sa.xp_all = xp_all; sa.gx_all = gx_all; sa.rproj = rproj; sa.b1 = b1;
    sa.bm = bm; sa.gam = gam; sa.bet = bet;
    sa.W1a = W1a; sa.W1b = W1b; sa.W1c = W1c;
    sa.Wma = Wma; sa.Wmb = Wmb; sa.Wmc = Wmc;
    sa.mp = mp; sa.qkvg = qkvg; sa.a1 = a1; sa.hbuf = hbuf; sa.m2 = m2;
    sa.out = out;
    void* kargs[] = { (void*)&sa };

    hipError_t ce = hipErrorUnknown;
    hipError_t ea = hipFuncSetAttribute((const void*)&scan_kernel<2>,
                                        hipFuncAttributeMaxDynamicSharedMemorySize,
                                        131072);
    if (ea == hipSuccess)
        ce = hipLaunchCooperativeKernel((void*)&scan_kernel<2>, dim3(NBLK),
                                        dim3(512), kargs, 131072, stream);
    if (ce != hipSuccess) {
        (void)hipFuncSetAttribute((const void*)&scan_kernel<1>,
                                  hipFuncAttributeMaxDynamicSharedMemorySize, 65536);
        ce = hipLaunchCooperativeKernel((void*)&scan_kernel<1>, dim3(NBLK),
                                        dim3(512), kargs, 65536, stream);
    }
    if (ce != hipSuccess) {
        // dispatch fallback (identical numerics)
        for (int t = 0; t < TT; ++t) {
            gemm6<<<dim3(40, 9), 256, 0, stream>>>(mp, W1a, W1b, W1c, b1,
                                                   qkvg, 5120, 0);
            attn_k<<<BB, 512, 0, stream>>>(sa);
            gemm6<<<dim3(8, 9), 256, 0, stream>>>(a1, Wma, Wmb, Wmc, bm,
                                                  hbuf, UU, 1);
            gemm6<<<dim3(8, 9), 256, 0, stream>>>(hbuf, Wma + (size_t)1024 * 1024,
                                                  Wmb + (size_t)1024 * 1024,
                                                  Wmc + (size_t)1024 * 1024,
                                                  bm + 1024, m2, UU, 0);
            finalize_k<<<MROWS, 512, 0, stream>>>(sa, t);
        }
    }
}

// Round 12
// 20861.838 us; speedup vs baseline: 2.2877x; 2.2877x over previous
//
#include <hip/hip_runtime.h>
#include <hip/hip_bf16.h>
#include <math.h>

// Problem config (fixed)
#define BB 32      // batch
#define TT 128     // time steps
#define UU 1024    // units
#define MM 8       // memory slots
#define LL 9       // M+1
#define RR 17      // 2M+1
#define MROWS 288  // BB*LL
#define RSC 4096.0f          // residual plane scale (2^12)
#define RSCI (1.0f/4096.0f)

typedef _Float16 f16x8 __attribute__((ext_vector_type(8)));
typedef float f32x4 __attribute__((ext_vector_type(4)));
typedef float f32x8 __attribute__((ext_vector_type(8)));

// fp16 split-2 with scaled residual: v ~= h1 + h2/4096, |err| <= 2^-22|v|
__device__ __forceinline__ void split2(float v, _Float16* h1, _Float16* h2)
{
    _Float16 a = (_Float16)v;
    float r = (v - (float)a) * RSC;
    *h1 = a; *h2 = (_Float16)r;
}

__device__ __forceinline__ void split2x8(const f32x8 v, f16x8& a, f16x8& b)
{
#pragma unroll
    for (int j = 0; j < 8; ++j) {
        float f = v[j];
        _Float16 h1 = (_Float16)f;
        float r = (f - (float)h1) * RSC;
        a[j] = h1; b[j] = (_Float16)r;
    }
}

__device__ __forceinline__ float gelu_f(float x)
{
    float t = tanhf(0.7978845608028654f * (x + 0.044715f * x * x * x));
    return 0.5f * x * (1.f + t);
}

// ================= K-split fp16-split2 MFMA GEMM (no LDS, no barriers) ======
// Partial[ks][MROWS][N] = A[MROWS, kslice] @ Bt[N, kslice]^T, kslice = KLEN.
// B given as plane1 (fp16) + plane2 (fp16, x4096). 3 MFMAs per fragment:
// accM += a1*b1 ; accR += a1*b2s + a2s*b1 ; result = accM + accR/4096.
// Block 256 thr = 4 waves in 2x2; wave tile 16 rows x CG*16 cols.
// bid = (g&7) + 8*(q + GdivP*rowT): same-B-slice blocks share an XCD.
template<int CG, int NKS, int KLEN>
__global__ __launch_bounds__(256) void gemmks(
    const float* __restrict__ A,
    const _Float16* __restrict__ B1, const _Float16* __restrict__ B2,
    float* __restrict__ P, int N, int GdivP)
{
    int tid = threadIdx.x, wave = tid >> 6, lane = tid & 63;
    int bid = blockIdx.x;
    int x = bid & 7, inner = bid >> 3;
    int q = inner % GdivP, rowT = inner / GdivP;
    int g = x + 8 * q;
    int colT = g / NKS, ks = g % NKS;

    int lr = lane & 15, kg = lane >> 4;
    int row0 = rowT * 32 + (wave & 1) * 16;
    int col0 = colT * (CG * 32) + (wave >> 1) * (CG * 16);
    int kbase = ks * KLEN;

    const float* Ap = A + (size_t)(row0 + lr) * 1024 + kbase + kg * 8;
    size_t boff = (size_t)(col0 + lr) * 1024 + kbase + kg * 8;

    f32x4 accM[CG], accR[CG];
#pragma unroll
    for (int c = 0; c < CG; ++c) {
        accM[c] = (f32x4){0.f, 0.f, 0.f, 0.f};
        accR[c] = (f32x4){0.f, 0.f, 0.f, 0.f};
    }

    for (int kc = 0; kc < KLEN; kc += 64) {
        // issue all loads for this 64-k chunk first (independent)
        f32x8 af0 = *(const f32x8*)(Ap + kc);
        f32x8 af1 = *(const f32x8*)(Ap + kc + 32);
        f16x8 bv[2][CG][2];
#pragma unroll
        for (int h = 0; h < 2; ++h)
#pragma unroll
            for (int c = 0; c < CG; ++c) {
                size_t o = boff + (size_t)c * 16 * 1024 + kc + h * 32;
                bv[h][c][0] = *(const f16x8*)(B1 + o);
                bv[h][c][1] = *(const f16x8*)(B2 + o);
            }
#pragma unroll
        for (int h = 0; h < 2; ++h) {
            f16x8 a1, a2s;
            split2x8(h ? af1 : af0, a1, a2s);
#pragma unroll
            for (int c = 0; c < CG; ++c) {
                accM[c] = __builtin_amdgcn_mfma_f32_16x16x32_f16(a1, bv[h][c][0], accM[c], 0, 0, 0);
                accR[c] = __builtin_amdgcn_mfma_f32_16x16x32_f16(a1, bv[h][c][1], accR[c], 0, 0, 0);
                accR[c] = __builtin_amdgcn_mfma_f32_16x16x32_f16(a2s, bv[h][c][0], accR[c], 0, 0, 0);
            }
        }
    }

    int r0 = row0 + kg * 4;
    float* Pk = P + (size_t)ks * MROWS * N;
#pragma unroll
    for (int c = 0; c < CG; ++c) {
        int col = col0 + c * 16 + lr;
#pragma unroll
        for (int r = 0; r < 4; ++r)
            Pk[(size_t)(r0 + r) * N + col] = accM[c][r] + accR[c][r] * RSCI;
    }
}

// combine 4 K-split partials + bias (+optional gelu)
__global__ __launch_bounds__(256) void add4(
    const float* __restrict__ P, const float* __restrict__ bias,
    float* __restrict__ out, int N, int act, int total4)
{
    int idx = blockIdx.x * 256 + threadIdx.x;
    if (idx >= total4) return;
    size_t e = (size_t)idx * 4;
    size_t SP = (size_t)MROWS * N;
    int col = (int)(e % N);
    f32x4 p0 = *(const f32x4*)(P + e);
    f32x4 p1 = *(const f32x4*)(P + SP + e);
    f32x4 p2 = *(const f32x4*)(P + 2 * SP + e);
    f32x4 p3 = *(const f32x4*)(P + 3 * SP + e);
    f32x4 bv = *(const f32x4*)(bias + col);
    f32x4 s;
#pragma unroll
    for (int j = 0; j < 4; ++j) {
        float v = ((p0[j] + p1[j]) + (p2[j] + p3[j])) + bv[j];
        s[j] = act ? gelu_f(v) : v;
    }
    *(f32x4*)(out + e) = s;
}

// ---- direct fp16-split2 GEMM (prep only): one 16x64 wave tile ----
__global__ __launch_bounds__(256) void gemm2(
    const float* __restrict__ A,
    const _Float16* __restrict__ B1, const _Float16* __restrict__ B2,
    const float* __restrict__ bias, float* __restrict__ C, int ldc, int act)
{
    int wave = threadIdx.x >> 6, lane = threadIdx.x & 63;
    int row0 = blockIdx.y * 32 + (wave >> 1) * 16;
    int col0 = blockIdx.x * 128 + (wave & 1) * 64;
    int lr = lane & 15, kofs = (lane >> 4) * 8;
    const float* Ap = A + (size_t)(row0 + lr) * 1024 + kofs;
    size_t boff = (size_t)(col0 + lr) * 1024 + kofs;
    f32x4 accM[4], accR[4];
#pragma unroll
    for (int c = 0; c < 4; ++c) {
        accM[c] = (f32x4){0.f, 0.f, 0.f, 0.f};
        accR[c] = (f32x4){0.f, 0.f, 0.f, 0.f};
    }
    for (int k = 0; k < 1024; k += 32) {
        f32x8 af = *(const f32x8*)(Ap + k);
        f16x8 a1, a2s;
        split2x8(af, a1, a2s);
#pragma unroll
        for (int c = 0; c < 4; ++c) {
            size_t o = boff + (size_t)c * 16 * 1024 + k;
            f16x8 b1 = *(const f16x8*)(B1 + o);
            f16x8 b2 = *(const f16x8*)(B2 + o);
            accM[c] = __builtin_amdgcn_mfma_f32_16x16x32_f16(a1, b1, accM[c], 0, 0, 0);
            accR[c] = __builtin_amdgcn_mfma_f32_16x16x32_f16(a1, b2, accR[c], 0, 0, 0);
            accR[c] = __builtin_amdgcn_mfma_f32_16x16x32_f16(a2s, b1, accR[c], 0, 0, 0);
        }
    }
    int r0 = row0 + (lane >> 4) * 4;
#pragma unroll
    for (int c = 0; c < 4; ++c) {
        int col = col0 + c * 16 + lr;
        float bv = bias ? bias[col] : 0.f;
#pragma unroll
        for (int r = 0; r < 4; ++r) {
            float v = accM[c][r] + accR[c][r] * RSCI + bv;
            if (act == 1) v = gelu_f(v);
            C[(size_t)(r0 + r) * ldc + col] = v;
        }
    }
}

// ---- weight transpose + fp16 split-2: planes[N,1024] from in[1024,N]^T ----
__global__ __launch_bounds__(256) void transpose_split(
    const float* __restrict__ in,
    _Float16* __restrict__ o1, _Float16* __restrict__ o2, int N)
{
    __shared__ float t[32][33];
    int tx = threadIdx.x & 31, ty = threadIdx.x >> 5;
    int k0 = blockIdx.y * 32, n0 = blockIdx.x * 32;
#pragma unroll
    for (int i = 0; i < 4; ++i)
        t[ty + i * 8][tx] = in[(size_t)(k0 + ty + i * 8) * N + n0 + tx];
    __syncthreads();
#pragma unroll
    for (int i = 0; i < 4; ++i) {
        float v = t[tx][ty + i * 8];
        size_t off = (size_t)(n0 + ty + i * 8) * 1024 + k0 + tx;
        split2(v, o1 + off, o2 + off);
    }
}

// ---------------- tiny fp32 GEMM (one-time rproj) ----------------
#define BKK 16
__global__ __launch_bounds__(256) void gemm_f32(
    const float* __restrict__ A, const float* __restrict__ B,
    float* __restrict__ C, int M, int N, int K)
{
    __shared__ float As[BKK][65];
    __shared__ float Bs[BKK][64];
    int tid = threadIdx.x;
    int row0 = blockIdx.y * 64, col0 = blockIdx.x * 64;
    int ty = tid >> 4, tx = tid & 15;
    float acc[4][4];
#pragma unroll
    for (int i = 0; i < 4; ++i)
#pragma unroll
        for (int j = 0; j < 4; ++j) acc[i][j] = 0.f;
    for (int k0 = 0; k0 < K; k0 += BKK) {
        {
            int r = tid >> 2, kv = (tid & 3) * 4;
            float4 v = make_float4(0.f, 0.f, 0.f, 0.f);
            int gr = row0 + r;
            if (gr < M) v = *(const float4*)(A + (size_t)gr * K + k0 + kv);
            As[kv + 0][r] = v.x; As[kv + 1][r] = v.y;
            As[kv + 2][r] = v.z; As[kv + 3][r] = v.w;
        }
        {
            int r = tid >> 4, cv = (tid & 15) * 4;
            float4 v = *(const float4*)(B + (size_t)(k0 + r) * N + col0 + cv);
            *(float4*)&Bs[r][cv] = v;
        }
        __syncthreads();
#pragma unroll
        for (int kk = 0; kk < BKK; ++kk) {
            float a[4], b[4];
#pragma unroll
            for (int j = 0; j < 4; ++j) a[j] = As[kk][ty * 4 + j];
#pragma unroll
            for (int j = 0; j < 4; ++j) b[j] = Bs[kk][tx * 4 + j];
#pragma unroll
            for (int i = 0; i < 4; ++i)
#pragma unroll
                for (int j = 0; j < 4; ++j) acc[i][j] += a[i] * b[j];
        }
        __syncthreads();
    }
#pragma unroll
    for (int i = 0; i < 4; ++i) {
        int gr = row0 + ty * 4 + i;
        if (gr >= M) continue;
#pragma unroll
        for (int j = 0; j < 4; ++j)
            C[(size_t)gr * N + col0 + tx * 4 + j] = acc[i][j];
    }
}

// ---------------- relative embedding table ----------------
__global__ void relemb_kernel(float* __restrict__ tab)
{
    int p = blockIdx.x;
    float pv = (float)(p - MM);
    for (int i = threadIdx.x; i < UU; i += blockDim.x) {
        float expo = (float)(i & ~1) * (1.0f / (float)UU);
        float scale = exp2f(-expo * 13.287712379549449f);  // 10000^-expo
        float ang = pv * scale;
        tab[p * UU + i] = (i & 1) ? cosf(ang) : sinf(ang);
    }
}

// ---------------- init mp ----------------
__global__ void init_mp(const float* __restrict__ xp_all, float* __restrict__ mp)
{
    int row = blockIdx.x;                 // 0..287
    int b = row / LL, l = row % LL;
    for (int u = threadIdx.x; u < UU; u += blockDim.x)
        mp[(size_t)row * UU + u] = (l == MM) ? xp_all[((size_t)b * TT) * UU + u] : 0.f;
}

// ---------------- attention + LN1 (one block per batch element) ----------------
__global__ __launch_bounds__(512) void attn_ln(
    const float* __restrict__ qkvg, const float* __restrict__ rproj,
    const float* __restrict__ mp,
    const float* __restrict__ gamma, const float* __restrict__ beta,
    float* __restrict__ a1)
{
    __shared__ float sA[LL][UU];
    __shared__ float red[16];
    int b = blockIdx.x;
    int tid = threadIdx.x;
    int wave = tid >> 6, lane = tid & 63;

    for (int hh = 0; hh < 2; ++hh) {
        int h = wave + hh * 8;
        const float* base = qkvg + (size_t)b * LL * 5120 + h * 64 + lane;
        float q[LL], k[LL], v[LL], r[RR];
#pragma unroll
        for (int l = 0; l < LL; ++l) {
            q[l] = base[l * 5120];
            k[l] = base[l * 5120 + 1024];
            v[l] = base[l * 5120 + 2048];
        }
#pragma unroll
        for (int rp = 0; rp < RR; ++rp) r[rp] = rproj[rp * UU + h * 64 + lane];
#pragma unroll
        for (int qr = 0; qr < LL; ++qr) {
            float sc[LL];
#pragma unroll
            for (int kr = 0; kr < LL; ++kr) {
                float prod = q[qr] * (k[kr] + r[qr - kr + MM]);
#pragma unroll
                for (int o = 32; o > 0; o >>= 1) prod += __shfl_xor(prod, o);
                sc[kr] = prod * 0.125f;
            }
            float m = sc[0];
#pragma unroll
            for (int kr = 1; kr < LL; ++kr) m = fmaxf(m, sc[kr]);
            float s = 0.f;
#pragma unroll
            for (int kr = 0; kr < LL; ++kr) { sc[kr] = expf(sc[kr] - m); s += sc[kr]; }
            float inv = 1.0f / s;
            float acc = 0.f;
#pragma unroll
            for (int kr = 0; kr < LL; ++kr) acc += sc[kr] * v[kr];
            sA[qr][h * 64 + lane] = acc * inv;
        }
    }
    __syncthreads();

    for (int l = 0; l < LL; ++l) {
        size_t row = (size_t)(b * LL + l);
        float x0 = mp[row * UU + tid] + sA[l][tid];
        float x1 = mp[row * UU + tid + 512] + sA[l][tid + 512];
        float s = x0 + x1, ss = x0 * x0 + x1 * x1;
#pragma unroll
        for (int o = 32; o > 0; o >>= 1) { s += __shfl_xor(s, o); ss += __shfl_xor(ss, o); }
        if (lane == 0) { red[wave * 2] = s; red[wave * 2 + 1] = ss; }
        __syncthreads();
        float S = 0.f, SS = 0.f;
#pragma unroll
        for (int w = 0; w < 8; ++w) { S += red[w * 2]; SS += red[w * 2 + 1]; }
        __syncthreads();
        float mean = S * (1.0f / UU);
        float var = SS * (1.0f / UU) - mean * mean;
        float rstd = rsqrtf(var + 1e-6f);
        a1[row * UU + tid]       = (x0 - mean) * rstd * gamma[tid] + beta[tid];
        a1[row * UU + tid + 512] = (x1 - mean) * rstd * gamma[tid + 512] + beta[tid + 512];
    }
}

// ------- finalize: combine m2 partials + LN2 + gates + memory update --------
__global__ __launch_bounds__(256) void finalize_step(
    const float* __restrict__ a1, const float* __restrict__ m2P,
    const float* __restrict__ bm,
    const float* __restrict__ qkvg, const float* __restrict__ gx_all,
    const float* __restrict__ xp_all,
    const float* __restrict__ gamma, const float* __restrict__ beta,
    float* __restrict__ mp, float* __restrict__ out, int t)
{
    __shared__ float red[8];
    int row = blockIdx.x;                 // 0..287
    int b = row / LL, l = row % LL;
    int tid = threadIdx.x;
    int wave = tid >> 6, lane = tid & 63;
    const size_t SP = (size_t)MROWS * UU;

    float x[4];
    float s = 0.f, ss = 0.f;
#pragma unroll
    for (int j = 0; j < 4; ++j) {
        int u = tid + j * 256;
        size_t off = (size_t)row * UU + u;
        float m2v = ((m2P[off] + m2P[SP + off]) + (m2P[2 * SP + off] + m2P[3 * SP + off]))
                    + bm[1024 + u];
        x[j] = a1[off] + m2v;
        s += x[j]; ss += x[j] * x[j];
    }
#pragma unroll
    for (int o = 32; o > 0; o >>= 1) { s += __shfl_xor(s, o); ss += __shfl_xor(ss, o); }
    if (lane == 0) { red[wave * 2] = s; red[wave * 2 + 1] = ss; }
    __syncthreads();
    float S = 0.f, SS = 0.f;
#pragma unroll
    for (int w = 0; w < 4; ++w) { S += red[w * 2]; SS += red[w * 2 + 1]; }
    float mean = S * (1.0f / UU);
    float rstd = rsqrtf(SS * (1.0f / UU) - mean * mean + 1e-6f);

    size_t gxoff = ((size_t)b * TT + t) * 2048;
    size_t grow = (size_t)row * 5120 + 3072;
#pragma unroll
    for (int j = 0; j < 4; ++j) {
        int u = tid + j * 256;
        float cand = (x[j] - mean) * rstd * gamma[1024 + u] + beta[1024 + u];
        float tc = tanhf(cand);
        float gi = gx_all[gxoff + u]        + qkvg[grow + u];
        float gf = gx_all[gxoff + 1024 + u] + qkvg[grow + 1024 + u];
        float ig = fminf(fmaxf(0.2f * gi + 0.5f, 0.f), 1.f);
        float fg = fminf(fmaxf(0.2f * (gf + 1.0f) + 0.5f, 0.f), 1.f);
        size_t off = (size_t)row * UU + u;
        float nmp = fg * mp[off] + ig * tc;
        if (l < MM) {
            mp[off] = nmp;
        } else {
            out[((size_t)b * TT + t) * UU + u] = nmp;
            if (t + 1 < TT)
                mp[off] = xp_all[((size_t)b * TT + t + 1) * UU + u];
        }
    }
}

// ---------------- host launcher ----------------
extern "C" void kernel_launch(void* const* d_in, const int* in_sizes, int n_in,
                              void* d_out, int out_size, void* d_ws, size_t ws_size,
                              hipStream_t stream)
{
    const float* x    = (const float*)d_in[0];
    const float* Wi   = (const float*)d_in[1];
    const float* bi   = (const float*)d_in[2];
    const float* Wg   = (const float*)d_in[3];
    const float* Wr   = (const float*)d_in[4];
    const float* br   = (const float*)d_in[5];
    const float* Wa   = (const float*)d_in[6];
    const float* ba   = (const float*)d_in[7];
    const float* Wm   = (const float*)d_in[8];
    const float* bm   = (const float*)d_in[9];
    const float* gam  = (const float*)d_in[10];
    const float* bet  = (const float*)d_in[11];
    const float* Wrel = (const float*)d_in[12];
    float* out = (float*)d_out;

    // ---- workspace layout ----
    char* w = (char*)d_ws;
    float*  xp_all = (float*)w;  w += (size_t)BB*TT*UU*4;        // 16.8 MB
    float*  gx_all = (float*)w;  w += (size_t)BB*TT*2048*4;      // 33.6 MB
    size_t W1N = (size_t)5120 * 1024, WMN = (size_t)2048 * 1024;
    _Float16* W1a = (_Float16*)w;  w += W1N*2;                   // 10.5 MB
    _Float16* W1b = (_Float16*)w;  w += W1N*2;                   // 10.5 MB
    _Float16* Wma = (_Float16*)w;  w += WMN*2;                   // 4.2 MB
    _Float16* Wmb = (_Float16*)w;  w += WMN*2;                   // 4.2 MB
    float*  b1    = (float*)w;   w += 5120*4;
    float*  tab   = (float*)w;   w += RR*UU*4;
    float*  rproj = (float*)w;   w += RR*UU*4;
    float*  mp    = (float*)w;   w += (size_t)MROWS*UU*4;
    float*  qkvg  = (float*)w;   w += (size_t)MROWS*5120*4;      // 5.9 MB
    float*  a1    = (float*)w;   w += (size_t)MROWS*UU*4;
    float*  hbuf  = (float*)w;   w += (size_t)MROWS*UU*4;
    // partials (qkvgP region aliased by prep-only Wi/Wg planes)
    char* sbase = w;
    float*  qkvgP = (float*)w;   w += (size_t)4*MROWS*5120*4;    // 23.6 MB
    float*  m1P   = (float*)w;   w += (size_t)4*MROWS*UU*4;      // 4.7 MB
    float*  m2P   = (float*)w;   w += (size_t)4*MROWS*UU*4;      // 4.7 MB
    _Float16* Wia = (_Float16*)sbase;
    _Float16* Wib = Wia + (size_t)1024 * 1024;
    _Float16* Wga = Wib + (size_t)1024 * 1024;
    _Float16* Wgb = Wga + (size_t)2048 * 1024;   // ends at 12.6 MB < 23.6 MB ✓

    // ---- one-time prep ----
    relemb_kernel<<<RR, 256, 0, stream>>>(tab);
    gemm_f32<<<dim3(UU / 64, 1), 256, 0, stream>>>(tab, Wrel, rproj, RR, UU, UU);
    transpose_split<<<dim3(3072 / 32, 32), 256, 0, stream>>>(Wa, W1a, W1b, 3072);
    transpose_split<<<dim3(2048 / 32, 32), 256, 0, stream>>>(
        Wr, W1a + (size_t)3072 * 1024, W1b + (size_t)3072 * 1024, 2048);
    transpose_split<<<dim3(2048 / 32, 32), 256, 0, stream>>>(Wm, Wma, Wmb, 2048);
    transpose_split<<<dim3(1024 / 32, 32), 256, 0, stream>>>(Wi, Wia, Wib, 1024);
    transpose_split<<<dim3(2048 / 32, 32), 256, 0, stream>>>(Wg, Wga, Wgb, 2048);
    hipMemcpyAsync(b1, ba, 3072 * sizeof(float), hipMemcpyDeviceToDevice, stream);
    hipMemcpyAsync(b1 + 3072, br, 2048 * sizeof(float), hipMemcpyDeviceToDevice, stream);
    gemm2<<<dim3(UU / 128, (BB * TT) / 32), 256, 0, stream>>>(
        x, Wia, Wib, bi, xp_all, UU, 0);
    gemm2<<<dim3(2048 / 128, (BB * TT) / 32), 256, 0, stream>>>(
        x, Wga, Wgb, nullptr, gx_all, 2048, 0);
    init_mp<<<MROWS, 256, 0, stream>>>(xp_all, mp);

    // ---- sequential scan (7 dispatches/step, R8 structure) ----
    // phase A: CG=2, NKS=4, KLEN=256: ncolT=80, g=320, GdivP=40, blocks=2880
    // MLPs:    CG=2, NKS=4, KLEN=256: ncolT=16, g=64,  GdivP=8,  blocks=576
    for (int t = 0; t < TT; ++t) {
        gemmks<2, 4, 256><<<2880, 256, 0, stream>>>(mp, W1a, W1b, qkvgP, 5120, 40);
        add4<<<(MROWS * 5120 / 4 + 255) / 256, 256, 0, stream>>>(
            qkvgP, b1, qkvg, 5120, 0, MROWS * 5120 / 4);
        attn_ln<<<BB, 512, 0, stream>>>(qkvg, rproj, mp, gam, bet, a1);
        gemmks<2, 4, 256><<<576, 256, 0, stream>>>(a1, Wma, Wmb, m1P, UU, 8);
        add4<<<(MROWS * UU / 4 + 255) / 256, 256, 0, stream>>>(
            m1P, bm, hbuf, UU, 1, MROWS * UU / 4);
        gemmks<2, 4, 256><<<576, 256, 0, stream>>>(hbuf, Wma + (size_t)1024 * 1024,
                                                   Wmb + (size_t)1024 * 1024, m2P, UU, 8);
        finalize_step<<<MROWS, 256, 0, stream>>>(a1, m2P, bm, qkvg, gx_all, xp_all,
                                                 gam, bet, mp, out, t);
    }
}